// Round 4
// baseline (605.350 us; speedup 1.0000x reference)
//
#include <hip/hip_runtime.h>
#include <math.h>

// Problem constants
#define BB 64
#define LL 25
#define FF 128
#define PP 10000

// ws layout (float offsets). Total ~9.03 MB.
// Partial-reduction slots (plain stores, no atomics, no init needed):
#define OFF_GEOP 0        // 64 blocks x [dsmax,dsmin,dtmax,dtmin]
#define OFF_TTP  256      // 64 x [ttmax,ttmin]
#define OFF_RRP  384      // 400 x [rowmax,rowmin]
#define OFF_TT   1184     // time_interval (B*L)
#define OFF_C1   2784     // 0.5*w_val[l]*exp(-tt/T1)  (B*L)
#define OFF_C2   4384     // 0.5*w_val[l]              (B*L)
#define OFF_DS   5984     // delta_s (B*625)
#define OFF_DT   45984    // delta_t (B*625)
#define OFF_SC   85984    // raw qk^T scores (B*625)
#define OFF_V    495584   // v (B*L*F)
// bf16 fragment-linear regions (addressed as unsigned short / bf16x8):
#define OFF_AH   700384   // sao hi  : 64b x 8kk x 64lane x 8j bf16 = 131072 floats
#define OFF_AL   831456   // sao lo
#define OFF_BH   962528   // poi_embT hi: 316tile x 8kk x 64lane x 8j = 647168 floats
#define OFF_BL   1609696  // poi_embT lo

// Fused front-kernel block ranges: heavy HBM-streaming rowred first, then the
// per-b fused blocks, then the light prep blocks.
#define NB_ROW  400
#define NB_BF   64
#define NB_PREP 625               // PP*FF/8 threads / 256 = exactly 625
#define NB_FRONT (NB_ROW + NB_BF + NB_PREP)   // 1089

#define NEG_INF -3.402823466e38f
#define POS_INF  3.402823466e38f

typedef short bf16x8 __attribute__((ext_vector_type(8)));
typedef float f32x16 __attribute__((ext_vector_type(16)));

// Round-to-nearest-even f32 -> bf16 bits, and back.
__device__ inline unsigned short f2bf(float x) {
    unsigned u = __float_as_uint(x);
    u += 0x7FFFu + ((u >> 16) & 1u);
    return (unsigned short)(u >> 16);
}
__device__ inline float bf2f(unsigned short h) {
    return __uint_as_float(((unsigned)h) << 16);
}

// Block-wide reduction (256 threads = 4 waves). Result valid in thread 0 only.
template <bool MAX>
__device__ float blockReduce(float v) {
    __shared__ float sh[8];
    const int lane = threadIdx.x & 63;
    const int wid  = threadIdx.x >> 6;
#pragma unroll
    for (int off = 32; off > 0; off >>= 1) {
        float o = __shfl_down(v, off, 64);
        v = MAX ? fmaxf(v, o) : fminf(v, o);
    }
    __syncthreads();           // protect sh reuse across sequential calls
    if (lane == 0) sh[wid] = v;
    __syncthreads();
    if (threadIdx.x == 0) {
        const int nw = blockDim.x >> 6;
        for (int w = 1; w < nw; ++w) v = MAX ? fmaxf(v, sh[w]) : fminf(v, sh[w]);
    }
    return v;
}

// Fused front kernel: 3 job types by block range.
//  [0,400):      rowred — max/min over 4 gathered dm rows per block → RRP.
//  [400,464):    bfused — per-b: geo (DS/DT/TT + partials), embeddings,
//                q/k/v matmuls (q,k stay in LDS — no ws round-trip), raw
//                QK^T scores → ws. v → ws for the PV stage.
//  [464,1089):   prep  — split poi_emb into bf16 hi/lo, B-fragment-linear.
__global__ void k_front(const int* __restrict__ user, const int* __restrict__ poi,
                        const int* __restrict__ tod, const int* __restrict__ dow,
                        const float* __restrict__ lat, const float* __restrict__ lon,
                        const float* __restrict__ ut,
                        const float* __restrict__ ue, const float* __restrict__ pe,
                        const float* __restrict__ te, const float* __restrict__ de,
                        const float* __restrict__ Wq, const float* __restrict__ bq,
                        const float* __restrict__ Wk, const float* __restrict__ bk,
                        const float* __restrict__ Wv, const float* __restrict__ bv,
                        const float* __restrict__ dm, float* __restrict__ ws) {
    const int blk = blockIdx.x, t = threadIdx.x;

    if (blk < NB_ROW) {
        // ---- rowred ----
        const int g = blk;   // [0,400)
        float mx = NEG_INF, mn = POS_INF;
#pragma unroll
        for (int rr = 0; rr < 4; ++rr) {
            const int r = poi[g * 4 + rr];
            const float4* row = (const float4*)(dm + (size_t)r * PP);
            for (int i = t; i < PP / 4; i += 256) {
                float4 v = row[i];
                mx = fmaxf(mx, fmaxf(fmaxf(v.x, v.y), fmaxf(v.z, v.w)));
                mn = fminf(mn, fminf(fminf(v.x, v.y), fminf(v.z, v.w)));
            }
        }
        float r2;
        r2 = blockReduce<true >(mx); if (!t) ws[OFF_RRP + g * 2 + 0] = r2;
        r2 = blockReduce<false>(mn); if (!t) ws[OFF_RRP + g * 2 + 1] = r2;

    } else if (blk < NB_ROW + NB_BF) {
        // ---- bfused (one block per b) ----
        const int b = blk - NB_ROW;
        __shared__ __align__(16) float xs[26 * FF];   // row 25 zeroed (pad row)
        __shared__ float qs[LL * 129], ks[LL * 129];  // stride 129: avoid conflicts
        __shared__ int ids[4][LL];
        __shared__ float la[LL], lo[LL], uu[LL];
        if (t < LL) {
            ids[0][t] = user[b * LL + t]; ids[1][t] = poi[b * LL + t];
            ids[2][t] = tod[b * LL + t];  ids[3][t] = dow[b * LL + t];
            la[t] = lat[b * LL + t]; lo[t] = lon[b * LL + t]; uu[t] = ut[b * LL + t];
        }
        if (t < FF) xs[LL * FF + t] = 0.0f;
        __syncthreads();
        // geo
        float dsmax = NEG_INF, dsmin = POS_INF, dtmax = NEG_INF, dtmin = POS_INF;
        const float pc = 0.017453292519943295f;  // pi/180
        for (int idx = t; idx < LL * LL; idx += 256) {
            int i = idx / LL, j = idx % LL;
            float a = 0.5f - cosf((la[j] - la[i]) * pc) * 0.5f
                    + cosf(la[i] * pc) * cosf(la[j] * pc) * (1.0f - cosf((lo[j] - lo[i]) * pc)) * 0.5f;
            float d  = 12742.0f * asinf(sqrtf(a));
            float dt = fabsf(uu[i] - uu[j]);
            ws[OFF_DS + b * 625 + idx] = d;
            ws[OFF_DT + b * 625 + idx] = dt;
            dsmax = fmaxf(dsmax, d); dsmin = fminf(dsmin, d);
            dtmax = fmaxf(dtmax, dt); dtmin = fminf(dtmin, dt);
        }
        float r;
        r = blockReduce<true >(dsmax); if (!t) ws[OFF_GEOP + b * 4 + 0] = r;
        r = blockReduce<false>(dsmin); if (!t) ws[OFF_GEOP + b * 4 + 1] = r;
        r = blockReduce<true >(dtmax); if (!t) ws[OFF_GEOP + b * 4 + 2] = r;
        r = blockReduce<false>(dtmin); if (!t) ws[OFF_GEOP + b * 4 + 3] = r;
        float ttv = 0.0f;
        if (t < LL) {
            ttv = (t == 0) ? 0.0f : fabsf(uu[t] - uu[t - 1]);
            ws[OFF_TT + b * LL + t] = ttv;
        }
        float tmax = (t < LL) ? ttv : NEG_INF;
        float tmin = (t < LL) ? ttv : POS_INF;
        r = blockReduce<true >(tmax); if (!t) ws[OFF_TTP + b * 2 + 0] = r;
        r = blockReduce<false>(tmin); if (!t) ws[OFF_TTP + b * 2 + 1] = r;
        // embeddings (once per b now, not 3x)
        for (int idx = t; idx < LL * FF; idx += 256) {
            int l = idx >> 7, f = idx & 127;
            xs[idx] = ue[ids[0][l] * FF + f] + pe[ids[1][l] * FF + f]
                    + te[ids[2][l] * FF + f] + de[ids[3][l] * FF + f];
        }
        __syncthreads();
        const int f  = t & 127;
        const int l0 = (t >> 7) * 13;
        auto mm = [&](const float* W, const float* bias, float* dstL, float* dstG) {
            float acc[13];
#pragma unroll
            for (int i = 0; i < 13; ++i) acc[i] = 0.0f;
            for (int g = 0; g < FF; g += 4) {
                float w0 = W[(g + 0) * FF + f];
                float w1 = W[(g + 1) * FF + f];
                float w2 = W[(g + 2) * FF + f];
                float w3 = W[(g + 3) * FF + f];
#pragma unroll
                for (int i = 0; i < 13; ++i) {
                    float4 x = *(const float4*)(xs + (l0 + i) * FF + g);
                    acc[i] = fmaf(x.w, w3, fmaf(x.z, w2, fmaf(x.y, w1, fmaf(x.x, w0, acc[i]))));
                }
            }
            float bb = bias[f];
#pragma unroll
            for (int i = 0; i < 13; ++i) {
                int l = l0 + i;
                if (l < LL) {
                    if (dstL) dstL[l * 129 + f] = acc[i] + bb;
                    else      dstG[l * FF  + f] = acc[i] + bb;
                }
            }
        };
        mm(Wq, bq, qs, nullptr);
        mm(Wk, bk, ks, nullptr);
        mm(Wv, bv, nullptr, ws + OFF_V + b * LL * FF);
        __syncthreads();
        // raw QK^T scores (delta added in k_mid once global extrema exist)
        for (int idx = t; idx < LL * LL; idx += 256) {
            int i = idx / LL, j = idx % LL;
            float a = 0.0f;
            for (int ff2 = 0; ff2 < FF; ++ff2)
                a = fmaf(qs[i * 129 + ff2], ks[j * 129 + ff2], a);
            ws[OFF_SC + b * 625 + idx] = a;
        }

    } else {
        // ---- prep ----
        const int gid = (blk - (NB_ROW + NB_BF)) * 256 + t;   // [0, 160000)
        const int p   = gid >> 4;
        const int sub = gid & 15;
        const int kk  = sub >> 1, kh = sub & 1;
        const float* src = pe + p * FF + kk * 16 + kh * 8;
        float4 a0 = *(const float4*)(src);
        float4 a1 = *(const float4*)(src + 4);
        float xv[8] = {a0.x, a0.y, a0.z, a0.w, a1.x, a1.y, a1.z, a1.w};
        bf16x8 hv, lv;
#pragma unroll
        for (int j = 0; j < 8; ++j) {
            unsigned short h = f2bf(xv[j]);
            hv[j] = (short)h;
            lv[j] = (short)f2bf(xv[j] - bf2f(h));
        }
        const int c = p >> 5, n = p & 31;
        const int pos = (c * 8 + kk) * 64 + (kh * 32 + n);   // units of 8 shorts
        ((bf16x8*)((unsigned short*)(ws + OFF_BH)))[pos] = hv;
        ((bf16x8*)((unsigned short*)(ws + OFF_BL)))[pos] = lv;
    }
}

// K_mid: delta + softmax + PV + A-frag emit, split by (b, f-half) -> 128 blocks.
// A-frags staged in LDS (zero-filled: rows 25..31 are now exact zeros, removing
// the stale-ws-read hazard) then written as 16B bf16x8 per lane.
__global__ void k_mid(const float* __restrict__ w_val, float* __restrict__ ws) {
    const int b = blockIdx.x, h = blockIdx.y, t = threadIdx.x;
    __shared__ float sc[LL * LL];
    __shared__ float vsh[LL * 64];
    __shared__ float bc[6];
    __shared__ __align__(16) unsigned short ahs[4 * 64 * 8], als[4 * 64 * 8];
    // reduce partials: [su,sl,tu,tl] from GEOP, [tu1,tl1] from TTP
    {
        float g0 = (t < 64) ? ws[OFF_GEOP + t * 4 + 0] : NEG_INF;
        float g1 = (t < 64) ? ws[OFF_GEOP + t * 4 + 1] : POS_INF;
        float g2 = (t < 64) ? ws[OFF_GEOP + t * 4 + 2] : NEG_INF;
        float g3 = (t < 64) ? ws[OFF_GEOP + t * 4 + 3] : POS_INF;
        float t0 = (t < 64) ? ws[OFF_TTP + t * 2 + 0] : NEG_INF;
        float t1 = (t < 64) ? ws[OFF_TTP + t * 2 + 1] : POS_INF;
        float r;
        r = blockReduce<true >(g0); if (!t) bc[0] = r;
        r = blockReduce<false>(g1); if (!t) bc[1] = r;
        r = blockReduce<true >(g2); if (!t) bc[2] = r;
        r = blockReduce<false>(g3); if (!t) bc[3] = r;
        r = blockReduce<true >(t0); if (!t) bc[4] = r;
        r = blockReduce<false>(t1); if (!t) bc[5] = r;
    }
    // stage raw scores + v-half; zero A-frag LDS
    for (int idx = t; idx < LL * LL; idx += 256) sc[idx] = ws[OFF_SC + b * 625 + idx];
    for (int idx = t; idx < LL * 64; idx += 256) {
        int l = idx >> 6, f0 = idx & 63;
        vsh[idx] = ws[OFF_V + b * LL * FF + l * FF + h * 64 + f0];
    }
    for (int idx = t; idx < 1024; idx += 256) {
        ((unsigned*)ahs)[idx] = 0u;
        ((unsigned*)als)[idx] = 0u;
    }
    __syncthreads();
    const float nS0 = -1.0f / (bc[0] - bc[1]);
    const float nT0 = -1.0f / (bc[2] - bc[3]);
    const float nT1 = -1.0f / (bc[4] - bc[5]);
    for (int idx = t; idx < LL * LL; idx += 256) {
        float d  = ws[OFF_DS + b * 625 + idx];
        float dt = ws[OFF_DT + b * 625 + idx];
        sc[idx] += 0.5f * (expf(d * nS0) + expf(dt * nT0));
    }
    __syncthreads();
    if (t < LL) {  // softmax over row t
        float m = NEG_INF;
        for (int j = 0; j < LL; ++j) m = fmaxf(m, sc[t * LL + j]);
        float s = 0.0f;
        for (int j = 0; j < LL; ++j) { float e = expf(sc[t * LL + j] - m); sc[t * LL + j] = e; s += e; }
        float inv = 1.0f / s;
        for (int j = 0; j < LL; ++j) sc[t * LL + j] *= inv;
    }
    __syncthreads();
    // PV for this f-half + emit split-bf16 into LDS A-frag layout
    for (int idx = t; idx < LL * 64; idx += 256) {
        int l = idx >> 6, f0 = idx & 63;
        float a = 0.0f;
        for (int j = 0; j < LL; ++j) a = fmaf(sc[l * LL + j], vsh[j * 64 + f0], a);
        unsigned short hh = f2bf(a);
        unsigned short lo = f2bf(a - bf2f(hh));
        int kk = f0 >> 4, kh = (f0 >> 3) & 1, jj = f0 & 7;
        int spos = (kk * 64 + (kh * 32 + l)) * 8 + jj;
        ahs[spos] = hh; als[spos] = lo;
    }
    __syncthreads();
    {   // vectorized A-frag writeback: exactly 256 chunks of 16B
        int kki = t >> 6, ln = t & 63;
        bf16x8 hv = *(const bf16x8*)(ahs + (kki * 64 + ln) * 8);
        bf16x8 lv = *(const bf16x8*)(als + (kki * 64 + ln) * 8);
        ((bf16x8*)((unsigned short*)(ws + OFF_AH)))[(b * 8 + h * 4 + kki) * 64 + ln] = hv;
        ((bf16x8*)((unsigned short*)(ws + OFF_AL)))[(b * 8 + h * 4 + kki) * 64 + ln] = lv;
    }
    if (h == 0 && t < LL) {
        float ttv = ws[OFF_TT + b * LL + t];
        float wv  = w_val[t];
        ws[OFF_C1 + b * LL + t] = 0.5f * wv * expf(ttv * nT1);
        ws[OFF_C2 + b * LL + t] = 0.5f * wv;
    }
}

// K6: MFMA candidate scoring. Block = 128-col tile (4 waves x 32 cols) x 4 b.
// Grid (79,16) = 1264 blocks (~5/CU) for gather-latency hiding. Per-block LDS
// staging only for the local 4 b (1.5 KB). B-fragments register-resident;
// split-bf16: C = Ah*Bh + Al*Bh + Ah*Bl. C/D map: col=lane&31,
// row=(reg&3)+8*(reg>>2)+4*(lane>>5); r=13..15 (rows>=25) dead -> skipped.
__global__ void __launch_bounds__(256) k_main(const int* __restrict__ poi,
                                              const float* __restrict__ dm,
                                              const float* __restrict__ bval_p,
                                              const float* __restrict__ ws,
                                              float* __restrict__ out) {
    const int t = threadIdx.x;
    const int wave = t >> 6, lane = t & 63;
    const int half = lane >> 5, col = lane & 31;
    __shared__ float lc1[4 * 32], lc2[4 * 32];
    __shared__ int   lrw[4 * 32];
    __shared__ float bc2[2];
    const int b0 = blockIdx.y * 4;
    // reduce rowred partials -> su1, sl1
    {
        float mx = NEG_INF, mn = POS_INF;
        for (int i = t; i < 400; i += 256) {
            mx = fmaxf(mx, ws[OFF_RRP + i * 2 + 0]);
            mn = fminf(mn, ws[OFF_RRP + i * 2 + 1]);
        }
        float r;
        r = blockReduce<true >(mx); if (!t) bc2[0] = r;
        r = blockReduce<false>(mn); if (!t) bc2[1] = r;
    }
    if (t < 4 * LL) {
        int bi = t / LL, l = t - bi * LL;
        lc1[bi * 32 + l] = ws[OFF_C1 + (b0 + bi) * LL + l];
        lc2[bi * 32 + l] = ws[OFF_C2 + (b0 + bi) * LL + l];
        lrw[bi * 32 + l] = poi[(b0 + bi) * LL + l];
    }
    __syncthreads();
    const float su1 = bc2[0], sl1 = bc2[1];
    const float nS1 = -1.0f / (su1 - sl1);
    const float bv  = bval_p[0];
    const int ct  = blockIdx.x * 4 + wave;          // 32-col tile
    const int p   = ct * 32 + col;
    const int pcl = min(p, PP - 1);                 // clamp: discard-only lanes stay in-bounds
    const bf16x8* Bh = (const bf16x8*)(ws + OFF_BH);
    const bf16x8* Bl = (const bf16x8*)(ws + OFF_BL);
    const bf16x8* Ah = (const bf16x8*)(ws + OFF_AH);
    const bf16x8* Al = (const bf16x8*)(ws + OFF_AL);
    bf16x8 bh[8], bl[8];
#pragma unroll
    for (int kk = 0; kk < 8; ++kk) {
        bh[kk] = Bh[(ct * 8 + kk) * 64 + lane];
        bl[kk] = Bl[(ct * 8 + kk) * 64 + lane];
    }
    for (int bi = 0; bi < 4; ++bi) {
        const int b = b0 + bi;
        f32x16 acc = {};
#pragma unroll
        for (int kk = 0; kk < 8; ++kk) {
            bf16x8 ah = Ah[(b * 8 + kk) * 64 + lane];
            bf16x8 al = Al[(b * 8 + kk) * 64 + lane];
            acc = __builtin_amdgcn_mfma_f32_32x32x16_bf16(ah, bh[kk], acc, 0, 0, 0);
            acc = __builtin_amdgcn_mfma_f32_32x32x16_bf16(al, bh[kk], acc, 0, 0, 0);
            acc = __builtin_amdgcn_mfma_f32_32x32x16_bf16(ah, bl[kk], acc, 0, 0, 0);
        }
        float sum = 0.0f;
#pragma unroll
        for (int r = 0; r < 13; ++r) {
            int row  = (r & 3) + 8 * (r >> 2) + 4 * half;   // r=12/half1 -> 28 (zero wt)
            int rowc = min(row, LL - 1);
            float d  = dm[(size_t)lrw[bi * 32 + rowc] * PP + pcl];
            float w  = lc1[bi * 32 + rowc] + lc2[bi * 32 + rowc] * __expf(d * nS1);
            w = (row < LL) ? w : 0.0f;
            sum = fmaf(w, acc[r], sum);
        }
        sum += __shfl_xor(sum, 32, 64);   // combine the two row-halves per col
        sum += bv;
        if (half == 0 && p < PP) {
            out[b * PP + p]           = sum;
            out[BB * PP + b * PP + p] = sum;
        }
    }
}

extern "C" void kernel_launch(void* const* d_in, const int* in_sizes, int n_in,
                              void* d_out, int out_size, void* d_ws, size_t ws_size,
                              hipStream_t stream) {
    const int*   user = (const int*)d_in[0];
    const int*   poi  = (const int*)d_in[1];
    // d_in[2] = cat (unused by reference)
    const float* lat  = (const float*)d_in[3];
    const float* lon  = (const float*)d_in[4];
    const int*   tod  = (const int*)d_in[5];
    const int*   dow  = (const int*)d_in[6];
    const float* ut   = (const float*)d_in[7];
    const float* ue   = (const float*)d_in[8];
    const float* pe   = (const float*)d_in[9];
    const float* te   = (const float*)d_in[10];
    const float* de   = (const float*)d_in[11];
    const float* Wq   = (const float*)d_in[12];
    const float* bq   = (const float*)d_in[13];
    const float* Wk   = (const float*)d_in[14];
    const float* bk   = (const float*)d_in[15];
    const float* Wv   = (const float*)d_in[16];
    const float* bv   = (const float*)d_in[17];
    const float* w_val = (const float*)d_in[18];
    const float* b_val = (const float*)d_in[19];
    const float* dm   = (const float*)d_in[20];
    float* out = (float*)d_out;
    float* ws  = (float*)d_ws;

    k_front<<<NB_FRONT, 256, 0, stream>>>(user, poi, tod, dow, lat, lon, ut,
                                          ue, pe, te, de, Wq, bq, Wk, bk, Wv, bv,
                                          dm, ws);
    k_mid<<<dim3(BB, 2), 256, 0, stream>>>(w_val, ws);
    k_main<<<dim3(79, 16), 256, 0, stream>>>(poi, dm, b_val, ws, out);
}

// Round 5
// 569.612 us; speedup vs baseline: 1.0627x; 1.0627x over previous
//
#include <hip/hip_runtime.h>
#include <math.h>

// Problem constants
#define BB 64
#define LL 25
#define FF 128
#define PP 10000

// ws layout (float offsets). Total ~9.03 MB.
// Partial-reduction slots (plain stores, no atomics, no init needed):
#define OFF_GEOP 0        // 64 blocks x [dsmax,dsmin,dtmax,dtmin]
#define OFF_TTP  256      // 64 x [ttmax,ttmin]
#define OFF_RRP  384      // 400 x [rowmax,rowmin]
#define OFF_TT   1184     // time_interval (B*L)
#define OFF_C1   2784     // 0.5*w_val[l]*exp(-tt/T1)  (B*L)
#define OFF_C2   4384     // 0.5*w_val[l]              (B*L)
#define OFF_DS   5984     // delta_s (B*625)
#define OFF_DT   45984    // delta_t (B*625)
#define OFF_Q    85984    // q (B*L*F)
#define OFF_K    290784
#define OFF_V    495584
// bf16 fragment-linear regions (addressed as unsigned short / bf16x8):
#define OFF_AH   700384   // sao hi  : 64b x 8kk x 64lane x 8j bf16 = 131072 floats
#define OFF_AL   831456   // sao lo
#define OFF_BH   962528   // poi_embT hi: 316tile x 8kk x 64lane x 8j = 647168 floats
#define OFF_BL   1609696  // poi_embT lo

// Fused front-kernel block ranges. Rowred (HBM-heavy, longest pole) dispatches
// FIRST so it starts at t=0; short prep blocks backfill CUs afterwards.
#define NB_ROW  400
#define NB_GEO  64
#define NB_QKV  192
#define NB_PREP 625               // PP*FF/8 threads / 256 = exactly 625
#define NB_FRONT (NB_ROW + NB_GEO + NB_QKV + NB_PREP)   // 1281

#define NEG_INF -3.402823466e38f
#define POS_INF  3.402823466e38f

typedef short bf16x8 __attribute__((ext_vector_type(8)));
typedef float f32x16 __attribute__((ext_vector_type(16)));

// Round-to-nearest-even f32 -> bf16 bits, and back.
__device__ inline unsigned short f2bf(float x) {
    unsigned u = __float_as_uint(x);
    u += 0x7FFFu + ((u >> 16) & 1u);
    return (unsigned short)(u >> 16);
}
__device__ inline float bf2f(unsigned short h) {
    return __uint_as_float(((unsigned)h) << 16);
}

// Block-wide reduction (256 threads = 4 waves). Result valid in thread 0 only.
template <bool MAX>
__device__ float blockReduce(float v) {
    __shared__ float sh[8];
    const int lane = threadIdx.x & 63;
    const int wid  = threadIdx.x >> 6;
#pragma unroll
    for (int off = 32; off > 0; off >>= 1) {
        float o = __shfl_down(v, off, 64);
        v = MAX ? fmaxf(v, o) : fminf(v, o);
    }
    __syncthreads();           // protect sh reuse across sequential calls
    if (lane == 0) sh[wid] = v;
    __syncthreads();
    if (threadIdx.x == 0) {
        const int nw = blockDim.x >> 6;
        for (int w = 1; w < nw; ++w) v = MAX ? fmaxf(v, sh[w]) : fminf(v, sh[w]);
    }
    return v;
}

// Fused front kernel: 4 independent jobs, selected by block range.
//  [0,400):      rowred — max/min over 4 gathered dm rows per block → RRP.
//  [400,464):    geo    — per-b haversine/delta_t/time_interval; partials → GEOP/TTP.
//  [464,656):    qkv    — embeddings + one of q/k/v per block.
//  [656,1281):   prep   — split poi_emb into bf16 hi/lo, B-fragment-linear.
__global__ void k_front(const int* __restrict__ user, const int* __restrict__ poi,
                        const int* __restrict__ tod, const int* __restrict__ dow,
                        const float* __restrict__ lat, const float* __restrict__ lon,
                        const float* __restrict__ ut,
                        const float* __restrict__ ue, const float* __restrict__ pe,
                        const float* __restrict__ te, const float* __restrict__ de,
                        const float* __restrict__ Wq, const float* __restrict__ bq,
                        const float* __restrict__ Wk, const float* __restrict__ bk,
                        const float* __restrict__ Wv, const float* __restrict__ bv,
                        const float* __restrict__ dm, float* __restrict__ ws) {
    const int blk = blockIdx.x, t = threadIdx.x;

    if (blk < NB_ROW) {
        // ---- rowred ----
        const int g = blk;   // [0,400)
        float mx = NEG_INF, mn = POS_INF;
#pragma unroll
        for (int rr = 0; rr < 4; ++rr) {
            const int r = poi[g * 4 + rr];
            const float4* row = (const float4*)(dm + (size_t)r * PP);
            for (int i = t; i < PP / 4; i += 256) {
                float4 v = row[i];
                mx = fmaxf(mx, fmaxf(fmaxf(v.x, v.y), fmaxf(v.z, v.w)));
                mn = fminf(mn, fminf(fminf(v.x, v.y), fminf(v.z, v.w)));
            }
        }
        float r2;
        r2 = blockReduce<true >(mx); if (!t) ws[OFF_RRP + g * 2 + 0] = r2;
        r2 = blockReduce<false>(mn); if (!t) ws[OFF_RRP + g * 2 + 1] = r2;

    } else if (blk < NB_ROW + NB_GEO) {
        // ---- geo ----
        const int b = blk - NB_ROW;
        __shared__ float la[LL], lo[LL], uu[LL];
        if (t < LL) { la[t] = lat[b * LL + t]; lo[t] = lon[b * LL + t]; uu[t] = ut[b * LL + t]; }
        __syncthreads();
        float dsmax = NEG_INF, dsmin = POS_INF, dtmax = NEG_INF, dtmin = POS_INF;
        const float p = 0.017453292519943295f;  // pi/180
        for (int idx = t; idx < LL * LL; idx += 256) {
            int i = idx / LL, j = idx % LL;
            float a = 0.5f - cosf((la[j] - la[i]) * p) * 0.5f
                    + cosf(la[i] * p) * cosf(la[j] * p) * (1.0f - cosf((lo[j] - lo[i]) * p)) * 0.5f;
            float d  = 12742.0f * asinf(sqrtf(a));
            float dt = fabsf(uu[i] - uu[j]);
            ws[OFF_DS + b * 625 + idx] = d;
            ws[OFF_DT + b * 625 + idx] = dt;
            dsmax = fmaxf(dsmax, d); dsmin = fminf(dsmin, d);
            dtmax = fmaxf(dtmax, dt); dtmin = fminf(dtmin, dt);
        }
        float r;
        r = blockReduce<true >(dsmax); if (!t) ws[OFF_GEOP + b * 4 + 0] = r;
        r = blockReduce<false>(dsmin); if (!t) ws[OFF_GEOP + b * 4 + 1] = r;
        r = blockReduce<true >(dtmax); if (!t) ws[OFF_GEOP + b * 4 + 2] = r;
        r = blockReduce<false>(dtmin); if (!t) ws[OFF_GEOP + b * 4 + 3] = r;
        // time_interval
        float ttv = 0.0f;
        if (t < LL) {
            ttv = (t == 0) ? 0.0f : fabsf(uu[t] - uu[t - 1]);
            ws[OFF_TT + b * LL + t] = ttv;
        }
        float tmax = (t < LL) ? ttv : NEG_INF;
        float tmin = (t < LL) ? ttv : POS_INF;
        r = blockReduce<true >(tmax); if (!t) ws[OFF_TTP + b * 2 + 0] = r;
        r = blockReduce<false>(tmin); if (!t) ws[OFF_TTP + b * 2 + 1] = r;

    } else if (blk < NB_ROW + NB_GEO + NB_QKV) {
        // ---- qkv ----
        const int id = blk - (NB_ROW + NB_GEO);
        const int b = id & 63, m = id >> 6;
        __shared__ __align__(16) float xs[26 * FF];   // row 25 zeroed (harmless pad row)
        __shared__ int ids[4][LL];
        if (t < LL) {
            ids[0][t] = user[b * LL + t]; ids[1][t] = poi[b * LL + t];
            ids[2][t] = tod[b * LL + t];  ids[3][t] = dow[b * LL + t];
        }
        if (t < FF) xs[LL * FF + t] = 0.0f;
        __syncthreads();
        for (int idx = t; idx < LL * FF; idx += 256) {
            int l = idx >> 7, f = idx & 127;
            xs[idx] = ue[ids[0][l] * FF + f] + pe[ids[1][l] * FF + f]
                    + te[ids[2][l] * FF + f] + de[ids[3][l] * FF + f];
        }
        __syncthreads();
        const float* W    = (m == 0) ? Wq : (m == 1) ? Wk : Wv;
        const float* bias = (m == 0) ? bq : (m == 1) ? bk : bv;
        float* o = ws + ((m == 0) ? OFF_Q : (m == 1) ? OFF_K : OFF_V) + b * LL * FF;
        const int f  = t & 127;
        const int l0 = (t >> 7) * 13;          // rows 0..12 or 13..24(+pad)
        float acc[13];
#pragma unroll
        for (int i = 0; i < 13; ++i) acc[i] = 0.0f;
        for (int g = 0; g < FF; g += 4) {
            float w0 = W[(g + 0) * FF + f];
            float w1 = W[(g + 1) * FF + f];
            float w2 = W[(g + 2) * FF + f];
            float w3 = W[(g + 3) * FF + f];
#pragma unroll
            for (int i = 0; i < 13; ++i) {
                float4 x = *(const float4*)(xs + (l0 + i) * FF + g);
                acc[i] = fmaf(x.w, w3, fmaf(x.z, w2, fmaf(x.y, w1, fmaf(x.x, w0, acc[i]))));
            }
        }
        float bb = bias[f];
#pragma unroll
        for (int i = 0; i < 13; ++i) {
            int l = l0 + i;
            if (l < LL) o[l * FF + f] = acc[i] + bb;   // wave-uniform guard
        }

    } else {
        // ---- prep ----
        const int gid = (blk - (NB_ROW + NB_GEO + NB_QKV)) * 256 + t;   // [0, 160000)
        const int p   = gid >> 4;
        const int sub = gid & 15;
        const int kk  = sub >> 1, kh = sub & 1;
        const float* src = pe + p * FF + kk * 16 + kh * 8;
        float4 a0 = *(const float4*)(src);
        float4 a1 = *(const float4*)(src + 4);
        float xv[8] = {a0.x, a0.y, a0.z, a0.w, a1.x, a1.y, a1.z, a1.w};
        bf16x8 hv, lv;
#pragma unroll
        for (int j = 0; j < 8; ++j) {
            unsigned short h = f2bf(xv[j]);
            hv[j] = (short)h;
            lv[j] = (short)f2bf(xv[j] - bf2f(h));
        }
        const int c = p >> 5, n = p & 31;
        const int pos = (c * 8 + kk) * 64 + (kh * 32 + n);   // units of 8 shorts
        ((bf16x8*)((unsigned short*)(ws + OFF_BH)))[pos] = hv;
        ((bf16x8*)((unsigned short*)(ws + OFF_BL)))[pos] = lv;
    }
}

// K5: per-b attention. First reduces the geo/tt partials (64 entries each, no
// atomics). sao emitted ONLY as split-bf16 MFMA A-fragments:
// A[m=l][k=kk*16+kh*8+j] at ((b*8+kk)*64 + (kh*32+l))*8 + j.
// A-frag slots for l=25..31 are ZERO-FILLED (they were previously never
// written: k_main's MFMA read poisoned ws — finite-poison-only safe).
__global__ void k_attn(const float* __restrict__ w_val, float* __restrict__ ws) {
    const int b = blockIdx.x, t = threadIdx.x;
    // stride 129 on q/k: stride 128 would be a 25-way bank conflict.
    __shared__ float qs[LL * 129], ks[LL * 129], vs[LL * FF], sc[LL * LL];
    __shared__ float bc[6];
    // reduce partials: [su,sl,tu,tl] from GEOP, [tu1,tl1] from TTP
    {
        float g0 = (t < 64) ? ws[OFF_GEOP + t * 4 + 0] : NEG_INF;
        float g1 = (t < 64) ? ws[OFF_GEOP + t * 4 + 1] : POS_INF;
        float g2 = (t < 64) ? ws[OFF_GEOP + t * 4 + 2] : NEG_INF;
        float g3 = (t < 64) ? ws[OFF_GEOP + t * 4 + 3] : POS_INF;
        float t0 = (t < 64) ? ws[OFF_TTP + t * 2 + 0] : NEG_INF;
        float t1 = (t < 64) ? ws[OFF_TTP + t * 2 + 1] : POS_INF;
        float r;
        r = blockReduce<true >(g0); if (!t) bc[0] = r;
        r = blockReduce<false>(g1); if (!t) bc[1] = r;
        r = blockReduce<true >(g2); if (!t) bc[2] = r;
        r = blockReduce<false>(g3); if (!t) bc[3] = r;
        r = blockReduce<true >(t0); if (!t) bc[4] = r;
        r = blockReduce<false>(t1); if (!t) bc[5] = r;
    }
    for (int idx = t; idx < LL * FF; idx += 256) {
        int l = idx >> 7, f = idx & 127;
        qs[l * 129 + f] = ws[OFF_Q + b * LL * FF + idx];
        ks[l * 129 + f] = ws[OFF_K + b * LL * FF + idx];
        vs[idx]         = ws[OFF_V + b * LL * FF + idx];
    }
    __syncthreads();
    const float su  = bc[0], sl  = bc[1];
    const float tu  = bc[2], tl  = bc[3];
    const float tu1 = bc[4], tl1 = bc[5];
    const float nS0 = -1.0f / (su - sl), nT0 = -1.0f / (tu - tl), nT1 = -1.0f / (tu1 - tl1);
    for (int idx = t; idx < LL * LL; idx += 256) {
        int i = idx / LL, j = idx % LL;
        float a = 0.0f;
        for (int f = 0; f < FF; ++f) a = fmaf(qs[i * 129 + f], ks[j * 129 + f], a);
        float d  = ws[OFF_DS + b * 625 + idx];
        float dt = ws[OFF_DT + b * 625 + idx];
        sc[idx] = a + 0.5f * (expf(d * nS0) + expf(dt * nT0));
    }
    __syncthreads();
    if (t < LL) {  // softmax over row t
        float m = NEG_INF;
        for (int j = 0; j < LL; ++j) m = fmaxf(m, sc[t * LL + j]);
        float s = 0.0f;
        for (int j = 0; j < LL; ++j) { float e = expf(sc[t * LL + j] - m); sc[t * LL + j] = e; s += e; }
        float inv = 1.0f / s;
        for (int j = 0; j < LL; ++j) sc[t * LL + j] *= inv;
    }
    __syncthreads();
    unsigned short* Ah = (unsigned short*)(ws + OFF_AH);
    unsigned short* Al = (unsigned short*)(ws + OFF_AL);
    for (int idx = t; idx < LL * FF; idx += 256) {
        int l = idx >> 7, f = idx & 127;
        float a = 0.0f;
        for (int j = 0; j < LL; ++j) a = fmaf(sc[l * LL + j], vs[j * FF + f], a);
        unsigned short h  = f2bf(a);
        unsigned short lo = f2bf(a - bf2f(h));
        int kk = f >> 4, kh = (f >> 3) & 1, j = f & 7;
        int pos = ((b * 8 + kk) * 64 + (kh * 32 + l)) * 8 + j;
        Ah[pos] = h; Al[pos] = lo;
    }
    // zero-fill A-frag rows l=25..31 (2 kh x 7 l x 8 kk = 112 bf16x8 slots per b)
    if (t < 112) {
        const int kk = t >> 4;            // t/16? no: 112 = 8kk*14; decode below
        const int u  = t;
        const int kki = u / 14;
        const int rem = u % 14;
        const int kh  = rem / 7;
        const int l   = 25 + rem % 7;
        bf16x8 z = {};
        ((bf16x8*)Ah)[(b * 8 + kki) * 64 + kh * 32 + l] = z;
        ((bf16x8*)Al)[(b * 8 + kki) * 64 + kh * 32 + l] = z;
        (void)kk;
    }
    if (t < LL) {
        float ttv = ws[OFF_TT + b * LL + t];
        float wv  = w_val[t];
        ws[OFF_C1 + b * LL + t] = 0.5f * wv * expf(ttv * nT1);
        ws[OFF_C2 + b * LL + t] = 0.5f * wv;
    }
}

// K6: MFMA candidate scoring. Block = 128-col tile (4 waves x 32 cols) x 8 b.
// Grid (79,8) = 632 blocks (~2.5/CU). Reduces RRP partials (400x2) at start.
// B-fragments (hi/lo) register-resident across the b-loop; split-bf16:
// C = Ah*Bh + Al*Bh + Ah*Bl. C/D map: col=lane&31,
// row=(reg&3)+8*(reg>>2)+4*(lane>>5); r=13..15 (rows>=25) dead -> skipped.
__global__ void __launch_bounds__(256) k_main(const int* __restrict__ poi,
                                              const float* __restrict__ dm,
                                              const float* __restrict__ bval_p,
                                              const float* __restrict__ ws,
                                              float* __restrict__ out) {
    const int t = threadIdx.x;
    const int wave = t >> 6, lane = t & 63;
    const int half = lane >> 5, col = lane & 31;
    __shared__ float lc1[BB * 32], lc2[BB * 32];
    __shared__ int   lrw[BB * 32];
    __shared__ float bc2[2];
    // reduce rowred partials -> su1, sl1
    {
        float mx = NEG_INF, mn = POS_INF;
        for (int i = t; i < 400; i += 256) {
            mx = fmaxf(mx, ws[OFF_RRP + i * 2 + 0]);
            mn = fminf(mn, ws[OFF_RRP + i * 2 + 1]);
        }
        float r;
        r = blockReduce<true >(mx); if (!t) bc2[0] = r;
        r = blockReduce<false>(mn); if (!t) bc2[1] = r;
    }
    for (int idx = t; idx < BB * LL; idx += 256) {
        int b = idx / LL, l = idx - b * LL;
        lc1[b * 32 + l] = ws[OFF_C1 + idx];
        lc2[b * 32 + l] = ws[OFF_C2 + idx];
        lrw[b * 32 + l] = poi[idx];
    }
    __syncthreads();
    const float su1 = bc2[0], sl1 = bc2[1];
    const float nS1 = -1.0f / (su1 - sl1);
    const float bv  = bval_p[0];
    const int ct  = blockIdx.x * 4 + wave;          // 32-col tile
    const int p   = ct * 32 + col;
    const int pcl = min(p, PP - 1);                 // clamp: discard-only lanes stay in-bounds
    const bf16x8* Bh = (const bf16x8*)(ws + OFF_BH);
    const bf16x8* Bl = (const bf16x8*)(ws + OFF_BL);
    const bf16x8* Ah = (const bf16x8*)(ws + OFF_AH);
    const bf16x8* Al = (const bf16x8*)(ws + OFF_AL);
    bf16x8 bh[8], bl[8];
#pragma unroll
    for (int kk = 0; kk < 8; ++kk) {
        bh[kk] = Bh[(ct * 8 + kk) * 64 + lane];
        bl[kk] = Bl[(ct * 8 + kk) * 64 + lane];
    }
    const int b0 = blockIdx.y * 8;
    for (int bi = 0; bi < 8; ++bi) {
        const int b = b0 + bi;
        f32x16 acc = {};
#pragma unroll
        for (int kk = 0; kk < 8; ++kk) {
            bf16x8 ah = Ah[(b * 8 + kk) * 64 + lane];
            bf16x8 al = Al[(b * 8 + kk) * 64 + lane];
            acc = __builtin_amdgcn_mfma_f32_32x32x16_bf16(ah, bh[kk], acc, 0, 0, 0);
            acc = __builtin_amdgcn_mfma_f32_32x32x16_bf16(al, bh[kk], acc, 0, 0, 0);
            acc = __builtin_amdgcn_mfma_f32_32x32x16_bf16(ah, bl[kk], acc, 0, 0, 0);
        }
        float sum = 0.0f;
        // r=13..15 -> rows 25..31 for both halves: dead (w=0), skipped.
#pragma unroll
        for (int r = 0; r < 13; ++r) {
            int row  = (r & 3) + 8 * (r >> 2) + 4 * half;   // r=12/half1 -> 28 (zero wt)
            int rowc = min(row, LL - 1);
            float d  = dm[(size_t)lrw[b * 32 + rowc] * PP + pcl];
            float w  = lc1[b * 32 + rowc] + lc2[b * 32 + rowc] * __expf(d * nS1);
            w = (row < LL) ? w : 0.0f;
            sum = fmaf(w, acc[r], sum);
        }
        sum += __shfl_xor(sum, 32, 64);   // combine the two row-halves per col
        sum += bv;
        if (half == 0 && p < PP) {
            out[b * PP + p]           = sum;
            out[BB * PP + b * PP + p] = sum;
        }
    }
}

extern "C" void kernel_launch(void* const* d_in, const int* in_sizes, int n_in,
                              void* d_out, int out_size, void* d_ws, size_t ws_size,
                              hipStream_t stream) {
    const int*   user = (const int*)d_in[0];
    const int*   poi  = (const int*)d_in[1];
    // d_in[2] = cat (unused by reference)
    const float* lat  = (const float*)d_in[3];
    const float* lon  = (const float*)d_in[4];
    const int*   tod  = (const int*)d_in[5];
    const int*   dow  = (const int*)d_in[6];
    const float* ut   = (const float*)d_in[7];
    const float* ue   = (const float*)d_in[8];
    const float* pe   = (const float*)d_in[9];
    const float* te   = (const float*)d_in[10];
    const float* de   = (const float*)d_in[11];
    const float* Wq   = (const float*)d_in[12];
    const float* bq   = (const float*)d_in[13];
    const float* Wk   = (const float*)d_in[14];
    const float* bk   = (const float*)d_in[15];
    const float* Wv   = (const float*)d_in[16];
    const float* bv   = (const float*)d_in[17];
    const float* w_val = (const float*)d_in[18];
    const float* b_val = (const float*)d_in[19];
    const float* dm   = (const float*)d_in[20];
    float* out = (float*)d_out;
    float* ws  = (float*)d_ws;

    k_front<<<NB_FRONT, 256, 0, stream>>>(user, poi, tod, dow, lat, lon, ut,
                                          ue, pe, te, de, Wq, bq, Wk, bk, Wv, bv,
                                          dm, ws);
    k_attn<<<BB, 256, 0, stream>>>(w_val, ws);
    k_main<<<dim3(79, 8), 256, 0, stream>>>(poi, dm, b_val, ws, out);
}